// Round 1
// baseline (428.595 us; speedup 1.0000x reference)
//
#include <hip/hip_runtime.h>

#define N_NODES 100000
#define N_EDGES 800000
#define EHALF (N_EDGES / 2)
#define H 128
#define MAX_Z 1000
#define N_GRAPHS 500
#define ELL_CAP 32
#define CTR0 0
#define CTR1 64

typedef __attribute__((ext_vector_type(8))) short bf16x8;
typedef __attribute__((ext_vector_type(4))) float f32x4;

__device__ __forceinline__ unsigned short f2bf(float f) {
    union { float f; unsigned u; } x; x.f = f;
    unsigned r = x.u + 0x7fffu + ((x.u >> 16) & 1u);   // RTNE
    return (unsigned short)(r >> 16);
}
__device__ __forceinline__ float bf2f(unsigned short u) {
    return __uint_as_float((unsigned)u << 16);
}
__device__ __forceinline__ int clampid(int p) {       // poison (0xAA..) is negative
    return (p < 0 || p >= N_NODES) ? 0 : p;
}

struct KP {
    const int* z; const int* esrc; const int* edst; const int* mask;
    const float* ztab; const float* W0; const float* W1; const float* W2;
    const float* b0; const float* b1; const float* b2;
    const float* l1w; const float* l1b; const float* l2w; const float* l2b;
    float* out;
    unsigned short* xb; unsigned short* xc; unsigned short* Wp; unsigned short* T0;
    int* fill; int* ell; int* f0; int* f1; int* list0; int* list1; int* ctrs; int* bar;
};

// monotonic device-wide barrier: all blocks co-resident by construction
// (grid = occupancy * 256 CUs). Release fence -> arrive -> spin -> acquire fence.
__device__ __forceinline__ void gbar(int* bar, int target) {
    __syncthreads();
    if (threadIdx.x == 0) {
        __threadfence();                                   // release (agent)
        __hip_atomic_fetch_add(bar, 1, __ATOMIC_RELAXED, __HIP_MEMORY_SCOPE_AGENT);
        while (__hip_atomic_load(bar, __ATOMIC_RELAXED, __HIP_MEMORY_SCOPE_AGENT) < target)
            __builtin_amdgcn_s_sleep(1);
        __threadfence();                                   // acquire (agent)
    }
    __syncthreads();
}

// one-wave GCN row aggregation from a bf16 feature array (2 cols/lane)
__device__ __forceinline__ void agg_row(const unsigned short* __restrict__ xin,
                                        const int* __restrict__ ell,
                                        const int* __restrict__ fill,
                                        int v, int lane, int l2,
                                        float& ax, float& ay) {
    int ntrue = fill[v];
    int px = 0;
    if (lane < ELL_CAP) px = ell[(size_t)v * ELL_CAP + lane];
    px = clampid(px);
    int fx = fill[px];
    ushort2 xs = *(const ushort2*)(xin + (size_t)v * H + l2);
    int n = ntrue > ELL_CAP ? ELL_CAP : ntrue;
    float dv = rsqrtf(1.0f + (float)ntrue);
    float pc = (lane < n) ? rsqrtf(1.0f + (float)fx) * dv : 0.f;
    float sc = dv * dv;
    ax = sc * bf2f(xs.x); ay = sc * bf2f(xs.y);
    int k = 0;
    for (; k + 3 < n; k += 4) {
        int s0 = __shfl(px, k),     s1 = __shfl(px, k + 1);
        int s2 = __shfl(px, k + 2), s3 = __shfl(px, k + 3);
        float c0 = __shfl(pc, k),     c1 = __shfl(pc, k + 1);
        float c2 = __shfl(pc, k + 2), c3 = __shfl(pc, k + 3);
        ushort2 m0 = *(const ushort2*)(xin + (size_t)s0 * H + l2);
        ushort2 m1 = *(const ushort2*)(xin + (size_t)s1 * H + l2);
        ushort2 m2 = *(const ushort2*)(xin + (size_t)s2 * H + l2);
        ushort2 m3 = *(const ushort2*)(xin + (size_t)s3 * H + l2);
        ax += c0 * bf2f(m0.x) + c1 * bf2f(m1.x) + c2 * bf2f(m2.x) + c3 * bf2f(m3.x);
        ay += c0 * bf2f(m0.y) + c1 * bf2f(m1.y) + c2 * bf2f(m2.y) + c3 * bf2f(m3.y);
    }
    for (; k < n; k++) {
        int s = __shfl(px, k); float c = __shfl(pc, k);
        ushort2 m0 = *(const ushort2*)(xin + (size_t)s * H + l2);
        ax += c * bf2f(m0.x); ay += c * bf2f(m0.y);
    }
}

__global__ __launch_bounds__(256, 3) void k_mega(KP p) {
    const int tid = threadIdx.x, bid = blockIdx.x;
    const int gdim = gridDim.x, nthr = gdim << 8;
    const int gtid = (bid << 8) + tid;
    const int lane = tid & 63, wv = tid >> 6;
    const int l2 = lane * 2;

    __shared__ unsigned short yt[16][136];
    __shared__ float ct[16][132];
    __shared__ int wtot[4];
    __shared__ int sb0, sb1, scnt1, scnt0;

    // ============ P1: W1/W2 pack + self-contained T0 GEMM + edge scan ======
    if (bid < 16) {                                  // pack W1, W2 (bf16 B-frag)
        int wi = 1 + (bid >> 3);
        const float* W = (wi == 1) ? p.W1 : p.W2;
        int t = (bid & 7) * 256 + tid;               // 0..2047
        int l = t & 63, kt = (t >> 6) & 3, c = t >> 8;
        int quad = l >> 4, n = c * 16 + (l & 15);
        unsigned short o[8];
#pragma unroll
        for (int j = 0; j < 8; j++) o[j] = f2bf(W[(kt * 32 + quad * 8 + j) * H + n]);
        ushort4 lo = { o[0], o[1], o[2], o[3] }, hi = { o[4], o[5], o[6], o[7] };
        unsigned short* dst = p.Wp + (size_t)wi * 16384 + (size_t)t * 8;
        *(ushort4*)(dst)     = lo;
        *(ushort4*)(dst + 4) = hi;
    }
    {   // T0 = bf16(ztab) @ bf16(W0), converting fp32 -> bf16 in-register
        int m = lane & 15, quad = lane >> 4;
        for (int t = bid; t < 63; t += gdim) {
            int row = t * 16 + m;
            const float* ar = p.ztab + (size_t)(row < MAX_Z ? row : 0) * H + quad * 8;
            bf16x8 A[4];
#pragma unroll
            for (int kk = 0; kk < 4; kk++) {
                float4 u  = *(const float4*)(ar + kk * 32);
                float4 v4 = *(const float4*)(ar + kk * 32 + 4);
                bf16x8 aa;
                aa[0] = (short)f2bf(u.x);  aa[1] = (short)f2bf(u.y);
                aa[2] = (short)f2bf(u.z);  aa[3] = (short)f2bf(u.w);
                aa[4] = (short)f2bf(v4.x); aa[5] = (short)f2bf(v4.y);
                aa[6] = (short)f2bf(v4.z); aa[7] = (short)f2bf(v4.w);
                A[kk] = aa;
            }
#pragma unroll
            for (int c2 = 0; c2 < 2; c2++) {
                int c = wv * 2 + c2;
                int n = c * 16 + m;
                f32x4 acc = (f32x4){0.f, 0.f, 0.f, 0.f};
#pragma unroll
                for (int kt = 0; kt < 4; kt++) {
                    bf16x8 bb;
#pragma unroll
                    for (int j = 0; j < 8; j++)
                        bb[j] = (short)f2bf(p.W0[(size_t)(kt * 32 + quad * 8 + j) * H + n]);
                    acc = __builtin_amdgcn_mfma_f32_16x16x32_bf16(A[kt], bb, acc, 0, 0, 0);
                }
                int r0 = t * 16 + quad * 4;
#pragma unroll
                for (int i2 = 0; i2 < 4; i2++) {
                    int r = r0 + i2;
                    if (r < MAX_Z) p.T0[(size_t)r * H + n] = f2bf(acc[i2]);
                }
            }
        }
    }
    for (int e = gtid; e < EHALF; e += nthr) {       // full edge scan, 2/thread
        int m0 = p.mask[e], m1 = p.mask[e + EHALF];
        int d0 = p.edst[e], d1 = p.edst[e + EHALF];
        int s0 = p.esrc[e], s1 = p.esrc[e + EHALF];
        if (m0) {
            int q = atomicAdd(&p.fill[d0], 1);
            if (q < ELL_CAP) p.ell[(size_t)d0 * ELL_CAP + q] = s0;
        }
        if (m1) {
            int q = atomicAdd(&p.fill[d1], 1);
            if (q < ELL_CAP) p.ell[(size_t)d1 * ELL_CAP + q] = s1;
        }
    }
    gbar(p.bar, gdim * 1);

    // ============ P2: N1 = centers U in(centers) ===========================
    for (int c0 = bid * 4; c0 < 2 * N_GRAPHS; c0 += gdim * 4) {
        int c = c0 + wv;
        int s = -1;
        if (c < 2 * N_GRAPHS) {
            int v = (c >> 1) * 200 + (c & 1);
            int n = p.fill[v]; if (n > ELL_CAP) n = ELL_CAP;
            s = (lane < n) ? p.ell[(size_t)v * ELL_CAP + lane] : ((lane == n) ? v : -1);
        }
        bool need = false;
        if (s >= 0 && atomicExch(&p.f1[s], 1) == 0) { p.f0[s] = 1; need = true; }
        unsigned long long b = __ballot(need);
        int total = __popcll(b);
        int pre = __popcll(b & ((1ull << lane) - 1ull));
        if (lane == 0) wtot[wv] = total;
        __syncthreads();
        if (tid == 0) {
            int bt = wtot[0] + wtot[1] + wtot[2] + wtot[3];
            if (bt) {
                sb1 = atomicAdd(&p.ctrs[CTR1], bt);
                sb0 = atomicAdd(&p.ctrs[CTR0], bt);
            }
        }
        __syncthreads();
        if (need) {
            int off = pre;
            for (int w2 = 0; w2 < 4; w2++) if (w2 < wv) off += wtot[w2];
            p.list1[sb1 + off] = s;
            p.list0[sb0 + off] = s;
        }
        __syncthreads();
    }
    gbar(p.bar, gdim * 2);

    if (tid == 0)
        scnt1 = __hip_atomic_load(&p.ctrs[CTR1], __ATOMIC_RELAXED, __HIP_MEMORY_SCOPE_AGENT);
    __syncthreads();
    const int cnt1 = scnt1;

    // ============ P3: N0 = N1 U in(N1) =====================================
    for (int base = bid * 4; base < cnt1; base += gdim * 4) {
        int i = base + wv;
        bool need = false;
        int s = 0;
        if (i < cnt1) {
            int v = p.list1[i];
            int n = p.fill[v]; if (n > ELL_CAP) n = ELL_CAP;
            if (lane < n) {
                s = p.ell[(size_t)v * ELL_CAP + lane];
                need = (atomicExch(&p.f0[s], 1) == 0);
            }
        }
        unsigned long long b = __ballot(need);
        int total = __popcll(b);
        int pre = __popcll(b & ((1ull << lane) - 1ull));
        if (lane == 0) wtot[wv] = total;
        __syncthreads();
        if (tid == 0) {
            int bt = wtot[0] + wtot[1] + wtot[2] + wtot[3];
            if (bt) sb0 = atomicAdd(&p.ctrs[CTR0], bt);
        }
        __syncthreads();
        if (need) {
            int off = pre;
            for (int w2 = 0; w2 < 4; w2++) if (w2 < wv) off += wtot[w2];
            p.list0[sb0 + off] = s;
        }
        __syncthreads();
    }
    gbar(p.bar, gdim * 3);

    if (tid == 0)
        scnt0 = __hip_atomic_load(&p.ctrs[CTR0], __ATOMIC_RELAXED, __HIP_MEMORY_SCOPE_AGENT);
    __syncthreads();
    const int cnt0 = scnt0;

    // ============ P4: layer 0 = T0-row aggregation + bias + ReLU -> xb =====
    {
        float2 bv = *(const float2*)(p.b0 + l2);
        for (int i = bid * 4 + wv; i < cnt0; i += gdim * 4) {
            int v = p.list0[i];
            int ntrue = p.fill[v];
            int px = 0;
            if (lane < ELL_CAP) px = p.ell[(size_t)v * ELL_CAP + lane];
            px = clampid(px);
            int zx = p.z[px];
            int fx = p.fill[px];
            int zv = p.z[v];
            int n = ntrue > ELL_CAP ? ELL_CAP : ntrue;
            float dv = rsqrtf(1.0f + (float)ntrue);
            float pc = (lane < n) ? rsqrtf(1.0f + (float)fx) * dv : 0.f;
            float sc = dv * dv;
            ushort2 xs = *(const ushort2*)(p.T0 + (size_t)zv * H + l2);
            float ax = sc * bf2f(xs.x) + bv.x;
            float ay = sc * bf2f(xs.y) + bv.y;
            int k = 0;
            for (; k + 3 < n; k += 4) {
                int z0 = __shfl(zx, k),     z1 = __shfl(zx, k + 1);
                int z2 = __shfl(zx, k + 2), z3 = __shfl(zx, k + 3);
                float c0 = __shfl(pc, k),     c1 = __shfl(pc, k + 1);
                float c2 = __shfl(pc, k + 2), c3 = __shfl(pc, k + 3);
                ushort2 m0 = *(const ushort2*)(p.T0 + (size_t)z0 * H + l2);
                ushort2 m1 = *(const ushort2*)(p.T0 + (size_t)z1 * H + l2);
                ushort2 m2 = *(const ushort2*)(p.T0 + (size_t)z2 * H + l2);
                ushort2 m3 = *(const ushort2*)(p.T0 + (size_t)z3 * H + l2);
                ax += c0 * bf2f(m0.x) + c1 * bf2f(m1.x) + c2 * bf2f(m2.x) + c3 * bf2f(m3.x);
                ay += c0 * bf2f(m0.y) + c1 * bf2f(m1.y) + c2 * bf2f(m2.y) + c3 * bf2f(m3.y);
            }
            for (; k < n; k++) {
                int zz = __shfl(zx, k); float c = __shfl(pc, k);
                ushort2 m0 = *(const ushort2*)(p.T0 + (size_t)zz * H + l2);
                ax += c * bf2f(m0.x); ay += c * bf2f(m0.y);
            }
            ushort2 o;
            o.x = f2bf(fmaxf(ax, 0.f));
            o.y = f2bf(fmaxf(ay, 0.f));
            *(ushort2*)(p.xb + (size_t)v * H + l2) = o;
        }
    }
    gbar(p.bar, gdim * 4);

    // ============ P5: layer 1 = agg(xb) + GEMM(W1) + bias + ReLU -> xc =====
    {
        const unsigned short* Wp1 = p.Wp + 16384;
        int m = lane & 15, quad = lane >> 4;
        for (int t = bid; t * 16 < cnt1; t += gdim) {
            for (int q = 0; q < 4; q++) {
                int r = t * 16 + wv * 4 + q;
                float ax = 0.f, ay = 0.f;
                if (r < cnt1) agg_row(p.xb, p.ell, p.fill, p.list1[r], lane, l2, ax, ay);
                ushort2 o; o.x = f2bf(ax); o.y = f2bf(ay);
                *(ushort2*)&yt[wv * 4 + q][l2] = o;
            }
            __syncthreads();
            bf16x8 a0 = *(const bf16x8*)&yt[m][quad * 8];
            bf16x8 a1 = *(const bf16x8*)&yt[m][32 + quad * 8];
            bf16x8 a2 = *(const bf16x8*)&yt[m][64 + quad * 8];
            bf16x8 a3 = *(const bf16x8*)&yt[m][96 + quad * 8];
#pragma unroll
            for (int c2 = 0; c2 < 2; c2++) {
                int c = wv * 2 + c2;
                const unsigned short* bp = Wp1 + ((size_t)(c * 4) * 64 + lane) * 8;
                bf16x8 b0 = *(const bf16x8*)(bp);
                bf16x8 b1 = *(const bf16x8*)(bp + 512);
                bf16x8 bf = *(const bf16x8*)(bp + 1024);
                bf16x8 b3 = *(const bf16x8*)(bp + 1536);
                f32x4 a = (f32x4){0.f, 0.f, 0.f, 0.f};
                a = __builtin_amdgcn_mfma_f32_16x16x32_bf16(a0, b0, a, 0, 0, 0);
                a = __builtin_amdgcn_mfma_f32_16x16x32_bf16(a1, b1, a, 0, 0, 0);
                a = __builtin_amdgcn_mfma_f32_16x16x32_bf16(a2, bf, a, 0, 0, 0);
                a = __builtin_amdgcn_mfma_f32_16x16x32_bf16(a3, b3, a, 0, 0, 0);
                int r0 = t * 16 + quad * 4, col = c * 16 + m;
                float bb = p.b1[col];
#pragma unroll
                for (int i2 = 0; i2 < 4; i2++) {
                    int r = r0 + i2;
                    if (r < cnt1)
                        p.xc[(size_t)p.list1[r] * H + col] = f2bf(fmaxf(a[i2] + bb, 0.f));
                }
            }
            __syncthreads();
        }
    }
    gbar(p.bar, gdim * 5);

    // ============ P6: layer 2 + hadamard pooling + MLP head ================
    for (int t = bid; t < 63; t += gdim) {
        for (int q = 0; q < 4; q++) {
            int idx = t * 16 + wv * 4 + q;
            float ax = 0.f, ay = 0.f;
            if (idx < 2 * N_GRAPHS) {
                int v = (idx >> 1) * 200 + (idx & 1);
                agg_row(p.xc, p.ell, p.fill, v, lane, l2, ax, ay);
            }
            ushort2 o; o.x = f2bf(ax); o.y = f2bf(ay);
            *(ushort2*)&yt[wv * 4 + q][l2] = o;
        }
        __syncthreads();
        int m = lane & 15, quad = lane >> 4;
        bf16x8 a0 = *(const bf16x8*)&yt[m][quad * 8];
        bf16x8 a1 = *(const bf16x8*)&yt[m][32 + quad * 8];
        bf16x8 a2 = *(const bf16x8*)&yt[m][64 + quad * 8];
        bf16x8 a3 = *(const bf16x8*)&yt[m][96 + quad * 8];
#pragma unroll
        for (int c2 = 0; c2 < 2; c2++) {
            int c = wv * 2 + c2;
            const unsigned short* bp = p.Wp + 32768 + ((size_t)(c * 4) * 64 + lane) * 8;
            bf16x8 b0 = *(const bf16x8*)(bp);
            bf16x8 b1 = *(const bf16x8*)(bp + 512);
            bf16x8 bf = *(const bf16x8*)(bp + 1024);
            bf16x8 b3 = *(const bf16x8*)(bp + 1536);
            f32x4 a = (f32x4){0.f, 0.f, 0.f, 0.f};
            a = __builtin_amdgcn_mfma_f32_16x16x32_bf16(a0, b0, a, 0, 0, 0);
            a = __builtin_amdgcn_mfma_f32_16x16x32_bf16(a1, b1, a, 0, 0, 0);
            a = __builtin_amdgcn_mfma_f32_16x16x32_bf16(a2, bf, a, 0, 0, 0);
            a = __builtin_amdgcn_mfma_f32_16x16x32_bf16(a3, b3, a, 0, 0, 0);
            int col = c * 16 + m;
            float bvv = p.b2[col];
#pragma unroll
            for (int i2 = 0; i2 < 4; i2++)
                ct[quad * 4 + i2][col] = a[i2] + bvv;
        }
        __syncthreads();
        // head: 8 graphs per stripe; 32 threads per graph, 4 output feats each
        int gl = tid >> 5, jq = tid & 31, j4 = jq * 4;
        int g = t * 8 + gl;
        float4 h = *(const float4*)(p.l1b + j4);
        const float* r0p = &ct[2 * gl][0];
        const float* r1p = &ct[2 * gl + 1][0];
#pragma unroll 4
        for (int k = 0; k < H; k++) {
            float pk = r0p[k] * r1p[k];
            float4 wv4 = *(const float4*)(p.l1w + (size_t)k * H + j4);
            h.x += pk * wv4.x; h.y += pk * wv4.y;
            h.z += pk * wv4.z; h.w += pk * wv4.w;
        }
        float4 l2v = *(const float4*)(p.l2w + j4);
        float s = fmaxf(h.x, 0.f) * l2v.x + fmaxf(h.y, 0.f) * l2v.y +
                  fmaxf(h.z, 0.f) * l2v.z + fmaxf(h.w, 0.f) * l2v.w;
#pragma unroll
        for (int d = 16; d > 0; d >>= 1) s += __shfl_xor(s, d, 32);
        if (jq == 0 && g < N_GRAPHS) p.out[g] = s + p.l2b[0];
        __syncthreads();
    }
}

extern "C" void kernel_launch(void* const* d_in, const int* in_sizes, int n_in,
                              void* d_out, int out_size, void* d_ws, size_t ws_size,
                              hipStream_t stream) {
    KP p;
    p.z    = (const int*)d_in[0];
    p.esrc = (const int*)d_in[1];
    p.edst = ((const int*)d_in[1]) + N_EDGES;
    p.mask = (const int*)d_in[3];
    p.ztab = (const float*)d_in[4];
    p.W0   = (const float*)d_in[5];
    p.b0   = (const float*)d_in[6];
    p.W1   = (const float*)d_in[7];
    p.b1   = (const float*)d_in[8];
    p.W2   = (const float*)d_in[9];
    p.b2   = (const float*)d_in[10];
    p.l1w  = (const float*)d_in[11];
    p.l1b  = (const float*)d_in[12];
    p.l2w  = (const float*)d_in[13];
    p.l2b  = (const float*)d_in[14];
    p.out  = (float*)d_out;

    char* w = (char*)d_ws;
    size_t o = 0;
    auto carve = [&](size_t bytes) { char* q = w + o; o = (o + bytes + 255) & ~(size_t)255; return q; };
    // zero-group first: one memset covers flags + counters + barrier
    p.fill  = (int*)carve((size_t)N_NODES * 4);
    p.f0    = (int*)carve((size_t)N_NODES * 4);
    p.f1    = (int*)carve((size_t)N_NODES * 4);
    p.ctrs  = (int*)carve(512);
    p.bar   = (int*)carve(256);
    const size_t zero_span = o;
    p.ell   = (int*)carve((size_t)N_NODES * ELL_CAP * 4);
    p.list0 = (int*)carve((size_t)N_NODES * 4);
    p.list1 = (int*)carve((size_t)40000 * 4);
    p.xb    = (unsigned short*)carve((size_t)N_NODES * H * 2);
    p.xc    = (unsigned short*)carve((size_t)N_NODES * H * 2);
    p.Wp    = (unsigned short*)carve((size_t)3 * 16384 * 2);
    p.T0    = (unsigned short*)carve((size_t)MAX_Z * H * 2);

    static int nblk = 0;
    if (nblk == 0) {
        int nb = 0;
        if (hipOccupancyMaxActiveBlocksPerMultiprocessor(&nb, k_mega, 256, 0) != hipSuccess || nb < 1)
            nb = 1;
        if (nb > 6) nb = 6;
        nblk = nb * 256;          // 256 CUs on MI355X; grid <= co-resident capacity
    }
    hipMemsetAsync(d_ws, 0, zero_span, stream);
    k_mega<<<nblk, 256, 0, stream>>>(p);
}

// Round 2
// 378.434 us; speedup vs baseline: 1.1325x; 1.1325x over previous
//
#include <hip/hip_runtime.h>

#define N_NODES 100000
#define N_EDGES 800000
#define EHALF (N_EDGES / 2)
#define H 128
#define MAX_Z 1000
#define N_GRAPHS 500
#define ELL_CAP 32
#define CTR0 0
#define CTR1 64

typedef __attribute__((ext_vector_type(8))) short bf16x8;
typedef __attribute__((ext_vector_type(4))) float f32x4;

__device__ __forceinline__ unsigned short f2bf(float f) {
    union { float f; unsigned u; } x; x.f = f;
    unsigned r = x.u + 0x7fffu + ((x.u >> 16) & 1u);   // RTNE
    return (unsigned short)(r >> 16);
}
__device__ __forceinline__ float bf2f(unsigned short u) {
    return __uint_as_float((unsigned)u << 16);
}
__device__ __forceinline__ int clampid(int p) {       // poison (0xAA..) is negative
    return (p < 0 || p >= N_NODES) ? 0 : p;
}

struct KP {
    const int* z; const int* esrc; const int* edst; const int* mask;
    const float* ztab; const float* W0; const float* W1; const float* W2;
    const float* b0; const float* b1; const float* b2;
    const float* l1w; const float* l1b; const float* l2w; const float* l2b;
    float* out;
    unsigned short* xb; unsigned short* xc; unsigned short* Wp; unsigned short* T0;
    int* fill; int* ell; int* f0; int* f1; int* list0; int* list1; int* ctrs; int* bar;
};

// Device-wide monotonic barrier, contention-safe version:
//  - arrival add carries RELEASE (prior writes visible to whoever observes it)
//  - poll is RELAXED with sleep backoff: total poll traffic < 1 G/s so the
//    LLC line's service rate (~2.4 G/s) is never saturated (round-1 failure:
//    s_sleep(1) polls from 1536 blocks = ~5 G/s -> ~50 us per barrier)
//  - one ACQUIRE load after the spin (release-sequence pairing), instead of
//    two full __threadfence() (wbl2+inv) per block per barrier
__device__ __forceinline__ void gbar(int* bar, int target) {
    __syncthreads();
    if (threadIdx.x == 0) {
        __hip_atomic_fetch_add(bar, 1, __ATOMIC_RELEASE, __HIP_MEMORY_SCOPE_AGENT);
        int spin = 0;
        while (__hip_atomic_load(bar, __ATOMIC_RELAXED, __HIP_MEMORY_SCOPE_AGENT) < target) {
            if (spin < 4) { __builtin_amdgcn_s_sleep(8); ++spin; }
            else          { __builtin_amdgcn_s_sleep(64); }
        }
        (void)__hip_atomic_load(bar, __ATOMIC_ACQUIRE, __HIP_MEMORY_SCOPE_AGENT);
    }
    __syncthreads();
}

// one-wave GCN row aggregation from a bf16 feature array (2 cols/lane)
__device__ __forceinline__ void agg_row(const unsigned short* __restrict__ xin,
                                        const int* __restrict__ ell,
                                        const int* __restrict__ fill,
                                        int v, int lane, int l2,
                                        float& ax, float& ay) {
    int ntrue = fill[v];
    int px = 0;
    if (lane < ELL_CAP) px = ell[(size_t)v * ELL_CAP + lane];
    px = clampid(px);
    int fx = fill[px];
    ushort2 xs = *(const ushort2*)(xin + (size_t)v * H + l2);
    int n = ntrue > ELL_CAP ? ELL_CAP : ntrue;
    float dv = rsqrtf(1.0f + (float)ntrue);
    float pc = (lane < n) ? rsqrtf(1.0f + (float)fx) * dv : 0.f;
    float sc = dv * dv;
    ax = sc * bf2f(xs.x); ay = sc * bf2f(xs.y);
    int k = 0;
    for (; k + 3 < n; k += 4) {
        int s0 = __shfl(px, k),     s1 = __shfl(px, k + 1);
        int s2 = __shfl(px, k + 2), s3 = __shfl(px, k + 3);
        float c0 = __shfl(pc, k),     c1 = __shfl(pc, k + 1);
        float c2 = __shfl(pc, k + 2), c3 = __shfl(pc, k + 3);
        ushort2 m0 = *(const ushort2*)(xin + (size_t)s0 * H + l2);
        ushort2 m1 = *(const ushort2*)(xin + (size_t)s1 * H + l2);
        ushort2 m2 = *(const ushort2*)(xin + (size_t)s2 * H + l2);
        ushort2 m3 = *(const ushort2*)(xin + (size_t)s3 * H + l2);
        ax += c0 * bf2f(m0.x) + c1 * bf2f(m1.x) + c2 * bf2f(m2.x) + c3 * bf2f(m3.x);
        ay += c0 * bf2f(m0.y) + c1 * bf2f(m1.y) + c2 * bf2f(m2.y) + c3 * bf2f(m3.y);
    }
    for (; k < n; k++) {
        int s = __shfl(px, k); float c = __shfl(pc, k);
        ushort2 m0 = *(const ushort2*)(xin + (size_t)s * H + l2);
        ax += c * bf2f(m0.x); ay += c * bf2f(m0.y);
    }
}

__global__ __launch_bounds__(256, 3) void k_mega(KP p) {
    const int tid = threadIdx.x, bid = blockIdx.x;
    const int gdim = gridDim.x, nthr = gdim << 8;
    const int gtid = (bid << 8) + tid;
    const int lane = tid & 63, wv = tid >> 6;
    const int l2 = lane * 2;

    __shared__ unsigned short yt[16][136];
    __shared__ float ct[16][132];
    __shared__ int wtot[4];
    __shared__ int sb0, sb1, scnt1, scnt0;

    // ============ P1: W1/W2 pack + self-contained T0 GEMM + edge scan ======
    if (bid < 16) {                                  // pack W1, W2 (bf16 B-frag)
        int wi = 1 + (bid >> 3);
        const float* W = (wi == 1) ? p.W1 : p.W2;
        int t = (bid & 7) * 256 + tid;               // 0..2047
        int l = t & 63, kt = (t >> 6) & 3, c = t >> 8;
        int quad = l >> 4, n = c * 16 + (l & 15);
        unsigned short o[8];
#pragma unroll
        for (int j = 0; j < 8; j++) o[j] = f2bf(W[(kt * 32 + quad * 8 + j) * H + n]);
        ushort4 lo = { o[0], o[1], o[2], o[3] }, hi = { o[4], o[5], o[6], o[7] };
        unsigned short* dst = p.Wp + (size_t)wi * 16384 + (size_t)t * 8;
        *(ushort4*)(dst)     = lo;
        *(ushort4*)(dst + 4) = hi;
    }
    {   // T0 = bf16(ztab) @ bf16(W0), converting fp32 -> bf16 in-register
        int m = lane & 15, quad = lane >> 4;
        for (int t = bid; t < 63; t += gdim) {
            int row = t * 16 + m;
            const float* ar = p.ztab + (size_t)(row < MAX_Z ? row : 0) * H + quad * 8;
            bf16x8 A[4];
#pragma unroll
            for (int kk = 0; kk < 4; kk++) {
                float4 u  = *(const float4*)(ar + kk * 32);
                float4 v4 = *(const float4*)(ar + kk * 32 + 4);
                bf16x8 aa;
                aa[0] = (short)f2bf(u.x);  aa[1] = (short)f2bf(u.y);
                aa[2] = (short)f2bf(u.z);  aa[3] = (short)f2bf(u.w);
                aa[4] = (short)f2bf(v4.x); aa[5] = (short)f2bf(v4.y);
                aa[6] = (short)f2bf(v4.z); aa[7] = (short)f2bf(v4.w);
                A[kk] = aa;
            }
#pragma unroll
            for (int c2 = 0; c2 < 2; c2++) {
                int c = wv * 2 + c2;
                int n = c * 16 + m;
                f32x4 acc = (f32x4){0.f, 0.f, 0.f, 0.f};
#pragma unroll
                for (int kt = 0; kt < 4; kt++) {
                    bf16x8 bb;
#pragma unroll
                    for (int j = 0; j < 8; j++)
                        bb[j] = (short)f2bf(p.W0[(size_t)(kt * 32 + quad * 8 + j) * H + n]);
                    acc = __builtin_amdgcn_mfma_f32_16x16x32_bf16(A[kt], bb, acc, 0, 0, 0);
                }
                int r0 = t * 16 + quad * 4;
#pragma unroll
                for (int i2 = 0; i2 < 4; i2++) {
                    int r = r0 + i2;
                    if (r < MAX_Z) p.T0[(size_t)r * H + n] = f2bf(acc[i2]);
                }
            }
        }
    }
    for (int e = gtid; e < EHALF; e += nthr) {       // full edge scan, 2/thread
        int m0 = p.mask[e], m1 = p.mask[e + EHALF];
        int d0 = p.edst[e], d1 = p.edst[e + EHALF];
        int s0 = p.esrc[e], s1 = p.esrc[e + EHALF];
        if (m0) {
            int q = atomicAdd(&p.fill[d0], 1);
            if (q < ELL_CAP) p.ell[(size_t)d0 * ELL_CAP + q] = s0;
        }
        if (m1) {
            int q = atomicAdd(&p.fill[d1], 1);
            if (q < ELL_CAP) p.ell[(size_t)d1 * ELL_CAP + q] = s1;
        }
    }
    gbar(p.bar, gdim * 1);

    // ============ P2: N1 = centers U in(centers) ===========================
    for (int c0 = bid * 4; c0 < 2 * N_GRAPHS; c0 += gdim * 4) {
        int c = c0 + wv;
        int s = -1;
        if (c < 2 * N_GRAPHS) {
            int v = (c >> 1) * 200 + (c & 1);
            int n = p.fill[v]; if (n > ELL_CAP) n = ELL_CAP;
            s = (lane < n) ? p.ell[(size_t)v * ELL_CAP + lane] : ((lane == n) ? v : -1);
        }
        bool need = false;
        if (s >= 0 && atomicExch(&p.f1[s], 1) == 0) { p.f0[s] = 1; need = true; }
        unsigned long long b = __ballot(need);
        int total = __popcll(b);
        int pre = __popcll(b & ((1ull << lane) - 1ull));
        if (lane == 0) wtot[wv] = total;
        __syncthreads();
        if (tid == 0) {
            int bt = wtot[0] + wtot[1] + wtot[2] + wtot[3];
            if (bt) {
                sb1 = atomicAdd(&p.ctrs[CTR1], bt);
                sb0 = atomicAdd(&p.ctrs[CTR0], bt);
            }
        }
        __syncthreads();
        if (need) {
            int off = pre;
            for (int w2 = 0; w2 < 4; w2++) if (w2 < wv) off += wtot[w2];
            p.list1[sb1 + off] = s;
            p.list0[sb0 + off] = s;
        }
        __syncthreads();
    }
    gbar(p.bar, gdim * 2);

    if (tid == 0)
        scnt1 = __hip_atomic_load(&p.ctrs[CTR1], __ATOMIC_RELAXED, __HIP_MEMORY_SCOPE_AGENT);
    __syncthreads();
    const int cnt1 = scnt1;

    // ============ P3: N0 = N1 U in(N1) =====================================
    for (int base = bid * 4; base < cnt1; base += gdim * 4) {
        int i = base + wv;
        bool need = false;
        int s = 0;
        if (i < cnt1) {
            int v = p.list1[i];
            int n = p.fill[v]; if (n > ELL_CAP) n = ELL_CAP;
            if (lane < n) {
                s = p.ell[(size_t)v * ELL_CAP + lane];
                need = (atomicExch(&p.f0[s], 1) == 0);
            }
        }
        unsigned long long b = __ballot(need);
        int total = __popcll(b);
        int pre = __popcll(b & ((1ull << lane) - 1ull));
        if (lane == 0) wtot[wv] = total;
        __syncthreads();
        if (tid == 0) {
            int bt = wtot[0] + wtot[1] + wtot[2] + wtot[3];
            if (bt) sb0 = atomicAdd(&p.ctrs[CTR0], bt);
        }
        __syncthreads();
        if (need) {
            int off = pre;
            for (int w2 = 0; w2 < 4; w2++) if (w2 < wv) off += wtot[w2];
            p.list0[sb0 + off] = s;
        }
        __syncthreads();
    }
    gbar(p.bar, gdim * 3);

    if (tid == 0)
        scnt0 = __hip_atomic_load(&p.ctrs[CTR0], __ATOMIC_RELAXED, __HIP_MEMORY_SCOPE_AGENT);
    __syncthreads();
    const int cnt0 = scnt0;

    // ============ P4: layer 0 = T0-row aggregation + bias + ReLU -> xb =====
    {
        float2 bv = *(const float2*)(p.b0 + l2);
        for (int i = bid * 4 + wv; i < cnt0; i += gdim * 4) {
            int v = p.list0[i];
            int ntrue = p.fill[v];
            int px = 0;
            if (lane < ELL_CAP) px = p.ell[(size_t)v * ELL_CAP + lane];
            px = clampid(px);
            int zx = p.z[px];
            int fx = p.fill[px];
            int zv = p.z[v];
            int n = ntrue > ELL_CAP ? ELL_CAP : ntrue;
            float dv = rsqrtf(1.0f + (float)ntrue);
            float pc = (lane < n) ? rsqrtf(1.0f + (float)fx) * dv : 0.f;
            float sc = dv * dv;
            ushort2 xs = *(const ushort2*)(p.T0 + (size_t)zv * H + l2);
            float ax = sc * bf2f(xs.x) + bv.x;
            float ay = sc * bf2f(xs.y) + bv.y;
            int k = 0;
            for (; k + 3 < n; k += 4) {
                int z0 = __shfl(zx, k),     z1 = __shfl(zx, k + 1);
                int z2 = __shfl(zx, k + 2), z3 = __shfl(zx, k + 3);
                float c0 = __shfl(pc, k),     c1 = __shfl(pc, k + 1);
                float c2 = __shfl(pc, k + 2), c3 = __shfl(pc, k + 3);
                ushort2 m0 = *(const ushort2*)(p.T0 + (size_t)z0 * H + l2);
                ushort2 m1 = *(const ushort2*)(p.T0 + (size_t)z1 * H + l2);
                ushort2 m2 = *(const ushort2*)(p.T0 + (size_t)z2 * H + l2);
                ushort2 m3 = *(const ushort2*)(p.T0 + (size_t)z3 * H + l2);
                ax += c0 * bf2f(m0.x) + c1 * bf2f(m1.x) + c2 * bf2f(m2.x) + c3 * bf2f(m3.x);
                ay += c0 * bf2f(m0.y) + c1 * bf2f(m1.y) + c2 * bf2f(m2.y) + c3 * bf2f(m3.y);
            }
            for (; k < n; k++) {
                int zz = __shfl(zx, k); float c = __shfl(pc, k);
                ushort2 m0 = *(const ushort2*)(p.T0 + (size_t)zz * H + l2);
                ax += c * bf2f(m0.x); ay += c * bf2f(m0.y);
            }
            ushort2 o;
            o.x = f2bf(fmaxf(ax, 0.f));
            o.y = f2bf(fmaxf(ay, 0.f));
            *(ushort2*)(p.xb + (size_t)v * H + l2) = o;
        }
    }
    gbar(p.bar, gdim * 4);

    // ============ P5: layer 1 = agg(xb) + GEMM(W1) + bias + ReLU -> xc =====
    {
        const unsigned short* Wp1 = p.Wp + 16384;
        int m = lane & 15, quad = lane >> 4;
        for (int t = bid; t * 16 < cnt1; t += gdim) {
            for (int q = 0; q < 4; q++) {
                int r = t * 16 + wv * 4 + q;
                float ax = 0.f, ay = 0.f;
                if (r < cnt1) agg_row(p.xb, p.ell, p.fill, p.list1[r], lane, l2, ax, ay);
                ushort2 o; o.x = f2bf(ax); o.y = f2bf(ay);
                *(ushort2*)&yt[wv * 4 + q][l2] = o;
            }
            __syncthreads();
            bf16x8 a0 = *(const bf16x8*)&yt[m][quad * 8];
            bf16x8 a1 = *(const bf16x8*)&yt[m][32 + quad * 8];
            bf16x8 a2 = *(const bf16x8*)&yt[m][64 + quad * 8];
            bf16x8 a3 = *(const bf16x8*)&yt[m][96 + quad * 8];
#pragma unroll
            for (int c2 = 0; c2 < 2; c2++) {
                int c = wv * 2 + c2;
                const unsigned short* bp = Wp1 + ((size_t)(c * 4) * 64 + lane) * 8;
                bf16x8 b0 = *(const bf16x8*)(bp);
                bf16x8 b1 = *(const bf16x8*)(bp + 512);
                bf16x8 bf = *(const bf16x8*)(bp + 1024);
                bf16x8 b3 = *(const bf16x8*)(bp + 1536);
                f32x4 a = (f32x4){0.f, 0.f, 0.f, 0.f};
                a = __builtin_amdgcn_mfma_f32_16x16x32_bf16(a0, b0, a, 0, 0, 0);
                a = __builtin_amdgcn_mfma_f32_16x16x32_bf16(a1, b1, a, 0, 0, 0);
                a = __builtin_amdgcn_mfma_f32_16x16x32_bf16(a2, bf, a, 0, 0, 0);
                a = __builtin_amdgcn_mfma_f32_16x16x32_bf16(a3, b3, a, 0, 0, 0);
                int r0 = t * 16 + quad * 4, col = c * 16 + m;
                float bb = p.b1[col];
#pragma unroll
                for (int i2 = 0; i2 < 4; i2++) {
                    int r = r0 + i2;
                    if (r < cnt1)
                        p.xc[(size_t)p.list1[r] * H + col] = f2bf(fmaxf(a[i2] + bb, 0.f));
                }
            }
            __syncthreads();
        }
    }
    gbar(p.bar, gdim * 5);

    // ============ P6: layer 2 + hadamard pooling + MLP head ================
    for (int t = bid; t < 63; t += gdim) {
        for (int q = 0; q < 4; q++) {
            int idx = t * 16 + wv * 4 + q;
            float ax = 0.f, ay = 0.f;
            if (idx < 2 * N_GRAPHS) {
                int v = (idx >> 1) * 200 + (idx & 1);
                agg_row(p.xc, p.ell, p.fill, v, lane, l2, ax, ay);
            }
            ushort2 o; o.x = f2bf(ax); o.y = f2bf(ay);
            *(ushort2*)&yt[wv * 4 + q][l2] = o;
        }
        __syncthreads();
        int m = lane & 15, quad = lane >> 4;
        bf16x8 a0 = *(const bf16x8*)&yt[m][quad * 8];
        bf16x8 a1 = *(const bf16x8*)&yt[m][32 + quad * 8];
        bf16x8 a2 = *(const bf16x8*)&yt[m][64 + quad * 8];
        bf16x8 a3 = *(const bf16x8*)&yt[m][96 + quad * 8];
#pragma unroll
        for (int c2 = 0; c2 < 2; c2++) {
            int c = wv * 2 + c2;
            const unsigned short* bp = p.Wp + 32768 + ((size_t)(c * 4) * 64 + lane) * 8;
            bf16x8 b0 = *(const bf16x8*)(bp);
            bf16x8 b1 = *(const bf16x8*)(bp + 512);
            bf16x8 bf = *(const bf16x8*)(bp + 1024);
            bf16x8 b3 = *(const bf16x8*)(bp + 1536);
            f32x4 a = (f32x4){0.f, 0.f, 0.f, 0.f};
            a = __builtin_amdgcn_mfma_f32_16x16x32_bf16(a0, b0, a, 0, 0, 0);
            a = __builtin_amdgcn_mfma_f32_16x16x32_bf16(a1, b1, a, 0, 0, 0);
            a = __builtin_amdgcn_mfma_f32_16x16x32_bf16(a2, bf, a, 0, 0, 0);
            a = __builtin_amdgcn_mfma_f32_16x16x32_bf16(a3, b3, a, 0, 0, 0);
            int col = c * 16 + m;
            float bvv = p.b2[col];
#pragma unroll
            for (int i2 = 0; i2 < 4; i2++)
                ct[quad * 4 + i2][col] = a[i2] + bvv;
        }
        __syncthreads();
        // head: 8 graphs per stripe; 32 threads per graph, 4 output feats each
        int gl = tid >> 5, jq = tid & 31, j4 = jq * 4;
        int g = t * 8 + gl;
        float4 h = *(const float4*)(p.l1b + j4);
        const float* r0p = &ct[2 * gl][0];
        const float* r1p = &ct[2 * gl + 1][0];
#pragma unroll 4
        for (int k = 0; k < H; k++) {
            float pk = r0p[k] * r1p[k];
            float4 wv4 = *(const float4*)(p.l1w + (size_t)k * H + j4);
            h.x += pk * wv4.x; h.y += pk * wv4.y;
            h.z += pk * wv4.z; h.w += pk * wv4.w;
        }
        float4 l2v = *(const float4*)(p.l2w + j4);
        float s = fmaxf(h.x, 0.f) * l2v.x + fmaxf(h.y, 0.f) * l2v.y +
                  fmaxf(h.z, 0.f) * l2v.z + fmaxf(h.w, 0.f) * l2v.w;
#pragma unroll
        for (int d = 16; d > 0; d >>= 1) s += __shfl_xor(s, d, 32);
        if (jq == 0 && g < N_GRAPHS) p.out[g] = s + p.l2b[0];
        __syncthreads();
    }
}

extern "C" void kernel_launch(void* const* d_in, const int* in_sizes, int n_in,
                              void* d_out, int out_size, void* d_ws, size_t ws_size,
                              hipStream_t stream) {
    KP p;
    p.z    = (const int*)d_in[0];
    p.esrc = (const int*)d_in[1];
    p.edst = ((const int*)d_in[1]) + N_EDGES;
    p.mask = (const int*)d_in[3];
    p.ztab = (const float*)d_in[4];
    p.W0   = (const float*)d_in[5];
    p.b0   = (const float*)d_in[6];
    p.W1   = (const float*)d_in[7];
    p.b1   = (const float*)d_in[8];
    p.W2   = (const float*)d_in[9];
    p.b2   = (const float*)d_in[10];
    p.l1w  = (const float*)d_in[11];
    p.l1b  = (const float*)d_in[12];
    p.l2w  = (const float*)d_in[13];
    p.l2b  = (const float*)d_in[14];
    p.out  = (float*)d_out;

    char* w = (char*)d_ws;
    size_t o = 0;
    auto carve = [&](size_t bytes) { char* q = w + o; o = (o + bytes + 255) & ~(size_t)255; return q; };
    // zero-group first: one memset covers flags + counters + barrier
    p.fill  = (int*)carve((size_t)N_NODES * 4);
    p.f0    = (int*)carve((size_t)N_NODES * 4);
    p.f1    = (int*)carve((size_t)N_NODES * 4);
    p.ctrs  = (int*)carve(512);
    p.bar   = (int*)carve(256);
    const size_t zero_span = o;
    p.ell   = (int*)carve((size_t)N_NODES * ELL_CAP * 4);
    p.list0 = (int*)carve((size_t)N_NODES * 4);
    p.list1 = (int*)carve((size_t)40000 * 4);
    p.xb    = (unsigned short*)carve((size_t)N_NODES * H * 2);
    p.xc    = (unsigned short*)carve((size_t)N_NODES * H * 2);
    p.Wp    = (unsigned short*)carve((size_t)3 * 16384 * 2);
    p.T0    = (unsigned short*)carve((size_t)MAX_Z * H * 2);

    static int nblk = 0;
    if (nblk == 0) {
        int nb = 0;
        if (hipOccupancyMaxActiveBlocksPerMultiprocessor(&nb, k_mega, 256, 0) != hipSuccess || nb < 1)
            nb = 1;
        if (nb > 8) nb = 8;
        nblk = nb * 256;          // 256 CUs on MI355X; grid <= co-resident capacity
    }
    hipMemsetAsync(d_ws, 0, zero_span, stream);
    k_mega<<<nblk, 256, 0, stream>>>(p);
}

// Round 3
// 175.344 us; speedup vs baseline: 2.4443x; 2.1582x over previous
//
#include <hip/hip_runtime.h>

#define N_NODES 100000
#define N_EDGES 800000
#define EHALF (N_EDGES / 2)
#define H 128
#define MAX_Z 1000
#define N_GRAPHS 500
#define ELL_CAP 32
#define EB 1563                  // edge blocks: ceil(400000/256)
#define CTR0 0
#define CTR1 64
#define AG_GRID 2048             // grid-stride blocks for k_agg0
#define LB_GRID 1040             // grid-stride blocks for k_layerB
#define N0_GRID 1024             // grid-stride blocks for k_n0

typedef __attribute__((ext_vector_type(8))) short bf16x8;
typedef __attribute__((ext_vector_type(4))) float f32x4;

__device__ __forceinline__ unsigned short f2bf(float f) {
    union { float f; unsigned u; } x; x.f = f;
    unsigned r = x.u + 0x7fffu + ((x.u >> 16) & 1u);   // RTNE
    return (unsigned short)(r >> 16);
}
__device__ __forceinline__ float bf2f(unsigned short u) {
    return __uint_as_float((unsigned)u << 16);
}
__device__ __forceinline__ int clampid(int p) {       // poison (0xAA..) is negative
    return (p < 0 || p >= N_NODES) ? 0 : p;
}

// ---- pass 1: full degree count (fire-and-forget atomics) + center ELL ----
// ---- plus: T0 = bf16(ztab) @ bf16(W0) GEMM, and W1/W2 bf16 B-frag pack ---
__global__ __launch_bounds__(256) void k_front(const int* __restrict__ esrc,
                                               const int* __restrict__ edst,
                                               const int* __restrict__ mask,
                                               int* deg, int* fill, int* ell,
                                               const float* __restrict__ ztab,
                                               const float* __restrict__ W0,
                                               const float* __restrict__ W1,
                                               const float* __restrict__ W2,
                                               unsigned short* Wp,
                                               unsigned short* T0) {
    int b = blockIdx.x, tid = threadIdx.x;
    if (b < EB) {
        int e = b * 256 + tid;
        if (e >= EHALF) return;
        int m0 = mask[e], m1 = mask[e + EHALF];
        int d0 = edst[e], d1 = edst[e + EHALF];
        int s0 = esrc[e], s1 = esrc[e + EHALF];
        if (m0) {
            atomicAdd(&deg[d0], 1);                    // no-return: throughput path
            if (d0 % 200 < 2) {                        // center node -> build ELL now
                int q = atomicAdd(&fill[d0], 1);
                if (q < ELL_CAP) ell[(size_t)d0 * ELL_CAP + q] = s0;
            }
        }
        if (m1) {
            atomicAdd(&deg[d1], 1);
            if (d1 % 200 < 2) {
                int q = atomicAdd(&fill[d1], 1);
                if (q < ELL_CAP) ell[(size_t)d1 * ELL_CAP + q] = s1;
            }
        }
    } else if (b < EB + 63) {
        // T0 GEMM tile t (0..62): fp32 ztab/W0 -> bf16 in-register -> MFMA
        int t = b - EB;
        int lane = tid & 63, wv = tid >> 6;
        int m = lane & 15, quad = lane >> 4;
        int row = t * 16 + m;
        const float* ar = ztab + (size_t)(row < MAX_Z ? row : 0) * H + quad * 8;
        bf16x8 A[4];
#pragma unroll
        for (int kk = 0; kk < 4; kk++) {
            float4 u  = *(const float4*)(ar + kk * 32);
            float4 v4 = *(const float4*)(ar + kk * 32 + 4);
            bf16x8 aa;
            aa[0] = (short)f2bf(u.x);  aa[1] = (short)f2bf(u.y);
            aa[2] = (short)f2bf(u.z);  aa[3] = (short)f2bf(u.w);
            aa[4] = (short)f2bf(v4.x); aa[5] = (short)f2bf(v4.y);
            aa[6] = (short)f2bf(v4.z); aa[7] = (short)f2bf(v4.w);
            A[kk] = aa;
        }
#pragma unroll
        for (int c2 = 0; c2 < 2; c2++) {
            int c = wv * 2 + c2;
            int n = c * 16 + m;
            f32x4 acc = (f32x4){0.f, 0.f, 0.f, 0.f};
#pragma unroll
            for (int kt = 0; kt < 4; kt++) {
                bf16x8 bb;
#pragma unroll
                for (int j = 0; j < 8; j++)
                    bb[j] = (short)f2bf(W0[(size_t)(kt * 32 + quad * 8 + j) * H + n]);
                acc = __builtin_amdgcn_mfma_f32_16x16x32_bf16(A[kt], bb, acc, 0, 0, 0);
            }
            int r0 = t * 16 + quad * 4;
#pragma unroll
            for (int i2 = 0; i2 < 4; i2++) {
                int r = r0 + i2;
                if (r < MAX_Z) T0[(size_t)r * H + n] = f2bf(acc[i2]);
            }
        }
    } else {
        int bb = b - EB - 63;                          // 0..15: pack W1, W2
        int wi = 1 + (bb >> 3);
        const float* W = (wi == 1) ? W1 : W2;
        int t = (bb & 7) * 256 + tid;                  // 0..2047
        int l = t & 63, kt = (t >> 6) & 3, c = t >> 8;
        int quad = l >> 4, n = c * 16 + (l & 15);
        unsigned short o[8];
#pragma unroll
        for (int j = 0; j < 8; j++) o[j] = f2bf(W[(kt * 32 + quad * 8 + j) * H + n]);
        ushort4 lo = { o[0], o[1], o[2], o[3] }, hi = { o[4], o[5], o[6], o[7] };
        unsigned short* dst = Wp + (size_t)wi * 16384 + (size_t)t * 8;
        *(ushort4*)(dst)     = lo;
        *(ushort4*)(dst + 4) = hi;
    }
}

// ---- N1 = centers U in(centers). Block-aggregated list allocation. -------
__global__ void k_n1(const int* deg, const int* ell, int* f1, int* f0,
                     int* list1, int* list0, int* ctrs) {
    __shared__ int wtot[4];
    __shared__ int bbase0, bbase1;
    int tid = threadIdx.x, lane = tid & 63, wv = tid >> 6;
    int c = blockIdx.x * 4 + wv;
    int s = -1;
    if (c < 2 * N_GRAPHS) {
        int v = (c >> 1) * 200 + (c & 1);
        int n = deg[v]; if (n > ELL_CAP) n = ELL_CAP;
        s = (lane < n) ? ell[(size_t)v * ELL_CAP + lane] : ((lane == n) ? v : -1);
    }
    bool need = false;
    if (s >= 0 && atomicExch(&f1[s], 1) == 0) {
        f0[s] = 1;                 // winner is unique; plain store suffices
        need = true;
    }
    unsigned long long b = __ballot(need);
    int total = __popcll(b);
    int pre = __popcll(b & ((1ull << lane) - 1ull));
    if (lane == 0) wtot[wv] = total;
    __syncthreads();
    if (tid == 0) {
        int bt = wtot[0] + wtot[1] + wtot[2] + wtot[3];
        if (bt) {
            bbase1 = atomicAdd(&ctrs[CTR1], bt);
            bbase0 = atomicAdd(&ctrs[CTR0], bt);
        }
    }
    __syncthreads();
    if (need) {
        int off = pre;
        for (int w2 = 0; w2 < 4; w2++) if (w2 < wv) off += wtot[w2];
        list1[bbase1 + off] = s;
        list0[bbase0 + off] = s;
    }
}

// ---- pass 2: ELL build for non-center N1 nodes (f1-filtered) -------------
__global__ void k_scan2(const int* __restrict__ esrc, const int* __restrict__ edst,
                        const int* __restrict__ mask, const int* __restrict__ f1,
                        int* fill, int* ell) {
    int e = blockIdx.x * 256 + threadIdx.x;
    if (e >= EHALF) return;
    int m0 = mask[e], m1 = mask[e + EHALF];
    int d0 = edst[e], d1 = edst[e + EHALF];
    int s0 = esrc[e], s1 = esrc[e + EHALF];
    if (m0 && d0 % 200 >= 2 && f1[d0]) {
        int q = atomicAdd(&fill[d0], 1);
        if (q < ELL_CAP) ell[(size_t)d0 * ELL_CAP + q] = s0;
    }
    if (m1 && d1 % 200 >= 2 && f1[d1]) {
        int q = atomicAdd(&fill[d1], 1);
        if (q < ELL_CAP) ell[(size_t)d1 * ELL_CAP + q] = s1;
    }
}

// ---- N0 = N1 U in(N1). Grid-stride; block-aggregated allocation. ---------
__global__ void k_n0(const int* deg, const int* ell, const int* list1,
                     int* f0, int* list0, int* ctrs) {
    __shared__ int wtot[4];
    __shared__ int bbase;
    int tid = threadIdx.x, lane = tid & 63, wv = tid >> 6;
    int cnt1 = ctrs[CTR1];
    for (int base = blockIdx.x * 4; base < cnt1; base += N0_GRID * 4) {
        int i = base + wv;
        bool need = false;
        int s = 0;
        if (i < cnt1) {
            int v = list1[i];
            int n = deg[v]; if (n > ELL_CAP) n = ELL_CAP;
            if (lane < n) {
                s = ell[(size_t)v * ELL_CAP + lane];
                need = (atomicExch(&f0[s], 1) == 0);
            }
        }
        unsigned long long b = __ballot(need);
        int total = __popcll(b);
        int pre = __popcll(b & ((1ull << lane) - 1ull));
        if (lane == 0) wtot[wv] = total;
        __syncthreads();
        if (tid == 0) {
            int bt = wtot[0] + wtot[1] + wtot[2] + wtot[3];
            if (bt) bbase = atomicAdd(&ctrs[CTR0], bt);
        }
        __syncthreads();
        if (need) {
            int off = pre;
            for (int w2 = 0; w2 < 4; w2++) if (w2 < wv) off += wtot[w2];
            list0[bbase + off] = s;
        }
        __syncthreads();
    }
}

// ---- pass 3: ELL build for N0 \ N1 nodes (f0 && !f1) ---------------------
__global__ void k_scan3(const int* __restrict__ esrc, const int* __restrict__ edst,
                        const int* __restrict__ mask, const int* __restrict__ f0,
                        const int* __restrict__ f1, int* fill, int* ell) {
    int e = blockIdx.x * 256 + threadIdx.x;
    if (e >= EHALF) return;
    int m0 = mask[e], m1 = mask[e + EHALF];
    int d0 = edst[e], d1 = edst[e + EHALF];
    int s0 = esrc[e], s1 = esrc[e + EHALF];
    if (m0 && f0[d0] && !f1[d0]) {
        int q = atomicAdd(&fill[d0], 1);
        if (q < ELL_CAP) ell[(size_t)d0 * ELL_CAP + q] = s0;
    }
    if (m1 && f0[d1] && !f1[d1]) {
        int q = atomicAdd(&fill[d1], 1);
        if (q < ELL_CAP) ell[(size_t)d1 * ELL_CAP + q] = s1;
    }
}

// ---- layer 0: pure aggregation of T0 rows + bias + ReLU -> xb ------------
__global__ __launch_bounds__(256) void k_agg0(const int* __restrict__ z,
                                              const unsigned short* __restrict__ T0,
                                              const int* __restrict__ ell,
                                              const int* __restrict__ deg,
                                              const int* __restrict__ list,
                                              const int* countp,
                                              const float* __restrict__ bias,
                                              unsigned short* xb) {
    int count = *countp;
    int tid = threadIdx.x, lane = tid & 63, wv = tid >> 6;
    int l2 = lane * 2;
    float2 bv = *(const float2*)(bias + l2);
    for (int i = blockIdx.x * 4 + wv; i < count; i += AG_GRID * 4) {
        int v = list[i];
        int ntrue = deg[v];
        int px = 0;
        if (lane < ELL_CAP) px = ell[(size_t)v * ELL_CAP + lane];
        px = clampid(px);              // poison-safe; lanes >= n unused
        int zx = z[px];
        int fx = deg[px];
        int zv = z[v];
        int n = ntrue > ELL_CAP ? ELL_CAP : ntrue;
        float dv = rsqrtf(1.0f + (float)ntrue);
        float pc = (lane < n) ? rsqrtf(1.0f + (float)fx) * dv : 0.f;
        float sc = dv * dv;
        ushort2 xs = *(const ushort2*)(T0 + (size_t)zv * H + l2);
        float ax = sc * bf2f(xs.x) + bv.x;
        float ay = sc * bf2f(xs.y) + bv.y;
        int k = 0;
        for (; k + 3 < n; k += 4) {
            int z0 = __shfl(zx, k),   z1 = __shfl(zx, k + 1);
            int z2 = __shfl(zx, k + 2), z3 = __shfl(zx, k + 3);
            float c0 = __shfl(pc, k),   c1 = __shfl(pc, k + 1);
            float c2 = __shfl(pc, k + 2), c3 = __shfl(pc, k + 3);
            ushort2 m0 = *(const ushort2*)(T0 + (size_t)z0 * H + l2);
            ushort2 m1 = *(const ushort2*)(T0 + (size_t)z1 * H + l2);
            ushort2 m2 = *(const ushort2*)(T0 + (size_t)z2 * H + l2);
            ushort2 m3 = *(const ushort2*)(T0 + (size_t)z3 * H + l2);
            ax += c0 * bf2f(m0.x) + c1 * bf2f(m1.x) + c2 * bf2f(m2.x) + c3 * bf2f(m3.x);
            ay += c0 * bf2f(m0.y) + c1 * bf2f(m1.y) + c2 * bf2f(m2.y) + c3 * bf2f(m3.y);
        }
        for (; k < n; k++) {
            int zz = __shfl(zx, k); float c = __shfl(pc, k);
            ushort2 m0 = *(const ushort2*)(T0 + (size_t)zz * H + l2);
            ax += c * bf2f(m0.x); ay += c * bf2f(m0.y);
        }
        ushort2 o;
        o.x = f2bf(fmaxf(ax, 0.f));
        o.y = f2bf(fmaxf(ay, 0.f));
        *(ushort2*)(xb + (size_t)v * H + l2) = o;
    }
}

// ---- fused layer B: agg from bf16 xin + GEMM + bias + ReLU -> xout -------
__global__ __launch_bounds__(512) void k_layerB(const unsigned short* __restrict__ xin,
                                                const int* __restrict__ ell,
                                                const int* __restrict__ deg,
                                                const int* __restrict__ list,
                                                const int* countp,
                                                const unsigned short* __restrict__ Wp,
                                                const float* __restrict__ bias,
                                                unsigned short* xout) {
    __shared__ unsigned short yt[16][136];
    int count = *countp;
    int tid = threadIdx.x, lane = tid & 63, wv = tid >> 6;   // wv 0..7
    int l2 = lane * 2;
    int m = lane & 15, quad = lane >> 4;

    for (int t = blockIdx.x; t * 16 < count; t += LB_GRID) {
        for (int q = 0; q < 2; q++) {
            int r = t * 16 + wv * 2 + q;
            float ax = 0.f, ay = 0.f;
            if (r < count) {
                int v = list[r];
                int ntrue = deg[v];
                int px = 0;
                if (lane < ELL_CAP) px = ell[(size_t)v * ELL_CAP + lane];
                px = clampid(px);
                int fx = deg[px];
                ushort2 xs = *(const ushort2*)(xin + (size_t)v * H + l2);
                int n = ntrue > ELL_CAP ? ELL_CAP : ntrue;
                float dv = rsqrtf(1.0f + (float)ntrue);
                float pc = (lane < n) ? rsqrtf(1.0f + (float)fx) * dv : 0.f;
                float sc = dv * dv;
                ax = sc * bf2f(xs.x); ay = sc * bf2f(xs.y);
                int k = 0;
                for (; k + 3 < n; k += 4) {
                    int s0 = __shfl(px, k),   s1 = __shfl(px, k + 1);
                    int s2 = __shfl(px, k + 2), s3 = __shfl(px, k + 3);
                    float c0 = __shfl(pc, k),   c1 = __shfl(pc, k + 1);
                    float c2 = __shfl(pc, k + 2), c3 = __shfl(pc, k + 3);
                    ushort2 m0 = *(const ushort2*)(xin + (size_t)s0 * H + l2);
                    ushort2 m1 = *(const ushort2*)(xin + (size_t)s1 * H + l2);
                    ushort2 m2 = *(const ushort2*)(xin + (size_t)s2 * H + l2);
                    ushort2 m3 = *(const ushort2*)(xin + (size_t)s3 * H + l2);
                    ax += c0 * bf2f(m0.x) + c1 * bf2f(m1.x) + c2 * bf2f(m2.x) + c3 * bf2f(m3.x);
                    ay += c0 * bf2f(m0.y) + c1 * bf2f(m1.y) + c2 * bf2f(m2.y) + c3 * bf2f(m3.y);
                }
                for (; k < n; k++) {
                    int s = __shfl(px, k); float c = __shfl(pc, k);
                    ushort2 m0 = *(const ushort2*)(xin + (size_t)s * H + l2);
                    ax += c * bf2f(m0.x); ay += c * bf2f(m0.y);
                }
            }
            ushort2 o; o.x = f2bf(ax); o.y = f2bf(ay);
            *(ushort2*)&yt[wv * 2 + q][l2] = o;
        }
        __syncthreads();

        bf16x8 a0 = *(const bf16x8*)&yt[m][quad * 8];
        bf16x8 a1 = *(const bf16x8*)&yt[m][32 + quad * 8];
        bf16x8 a2 = *(const bf16x8*)&yt[m][64 + quad * 8];
        bf16x8 a3 = *(const bf16x8*)&yt[m][96 + quad * 8];
        const unsigned short* bp = Wp + ((size_t)(wv * 4) * 64 + lane) * 8;
        bf16x8 b0 = *(const bf16x8*)(bp);
        bf16x8 b1 = *(const bf16x8*)(bp + 64 * 8);
        bf16x8 b2 = *(const bf16x8*)(bp + 128 * 8);
        bf16x8 b3 = *(const bf16x8*)(bp + 192 * 8);
        f32x4 a = (f32x4){0.f, 0.f, 0.f, 0.f};
        a = __builtin_amdgcn_mfma_f32_16x16x32_bf16(a0, b0, a, 0, 0, 0);
        a = __builtin_amdgcn_mfma_f32_16x16x32_bf16(a1, b1, a, 0, 0, 0);
        a = __builtin_amdgcn_mfma_f32_16x16x32_bf16(a2, b2, a, 0, 0, 0);
        a = __builtin_amdgcn_mfma_f32_16x16x32_bf16(a3, b3, a, 0, 0, 0);

        int r0 = t * 16 + quad * 4;
        int col = wv * 16 + m;
        float bv = bias[col];
#pragma unroll
        for (int i = 0; i < 4; i++) {
            int r = r0 + i;
            if (r < count)
                xout[(size_t)list[r] * H + col] = f2bf(fmaxf(a[i] + bv, 0.f));
        }
        __syncthreads();   // protect yt before next stride iteration
    }
}

// ---- fused layer 2 + head: agg at centers + GEMM + hadamard + MLP --------
__global__ __launch_bounds__(256) void k_layer2(const unsigned short* __restrict__ xin,
                                                const int* __restrict__ ell,
                                                const int* __restrict__ deg,
                                                const unsigned short* __restrict__ Wp,
                                                const float* b2,
                                                const float* l1w, const float* l1b,
                                                const float* l2w, const float* l2b,
                                                float* out) {
    __shared__ unsigned short yt[16][136];
    __shared__ float ct[16][132];
    int t = blockIdx.x;                       // 0..62
    int tid = threadIdx.x, lane = tid & 63, wv = tid >> 6;
    int l2 = lane * 2;

    for (int q = 0; q < 4; q++) {
        int idx = t * 16 + wv * 4 + q;
        float ax = 0.f, ay = 0.f;
        if (idx < 2 * N_GRAPHS) {
            int v = (idx >> 1) * 200 + (idx & 1);
            int ntrue = deg[v];
            int px = 0;
            if (lane < ELL_CAP) px = ell[(size_t)v * ELL_CAP + lane];
            px = clampid(px);
            int fx = deg[px];
            ushort2 xs = *(const ushort2*)(xin + (size_t)v * H + l2);
            int n = ntrue > ELL_CAP ? ELL_CAP : ntrue;
            float dv = rsqrtf(1.0f + (float)ntrue);
            float pc = (lane < n) ? rsqrtf(1.0f + (float)fx) * dv : 0.f;
            float sc = dv * dv;
            ax = sc * bf2f(xs.x); ay = sc * bf2f(xs.y);
            int k = 0;
            for (; k + 3 < n; k += 4) {
                int s0 = __shfl(px, k),   s1 = __shfl(px, k + 1);
                int s2 = __shfl(px, k + 2), s3 = __shfl(px, k + 3);
                float c0 = __shfl(pc, k),   c1 = __shfl(pc, k + 1);
                float c2 = __shfl(pc, k + 2), c3 = __shfl(pc, k + 3);
                ushort2 m0 = *(const ushort2*)(xin + (size_t)s0 * H + l2);
                ushort2 m1 = *(const ushort2*)(xin + (size_t)s1 * H + l2);
                ushort2 m2 = *(const ushort2*)(xin + (size_t)s2 * H + l2);
                ushort2 m3 = *(const ushort2*)(xin + (size_t)s3 * H + l2);
                ax += c0 * bf2f(m0.x) + c1 * bf2f(m1.x) + c2 * bf2f(m2.x) + c3 * bf2f(m3.x);
                ay += c0 * bf2f(m0.y) + c1 * bf2f(m1.y) + c2 * bf2f(m2.y) + c3 * bf2f(m3.y);
            }
            for (; k < n; k++) {
                int s = __shfl(px, k); float c = __shfl(pc, k);
                ushort2 m0 = *(const ushort2*)(xin + (size_t)s * H + l2);
                ax += c * bf2f(m0.x); ay += c * bf2f(m0.y);
            }
        }
        ushort2 o; o.x = f2bf(ax); o.y = f2bf(ay);
        *(ushort2*)&yt[wv * 4 + q][l2] = o;
    }
    __syncthreads();

    int m = lane & 15, quad = lane >> 4;
    bf16x8 a0 = *(const bf16x8*)&yt[m][quad * 8];
    bf16x8 a1 = *(const bf16x8*)&yt[m][32 + quad * 8];
    bf16x8 a2 = *(const bf16x8*)&yt[m][64 + quad * 8];
    bf16x8 a3 = *(const bf16x8*)&yt[m][96 + quad * 8];

#pragma unroll
    for (int c2 = 0; c2 < 2; c2++) {
        int c = wv * 2 + c2;
        const unsigned short* bp = Wp + ((size_t)(c * 4) * 64 + lane) * 8;
        bf16x8 b0 = *(const bf16x8*)(bp);
        bf16x8 b1 = *(const bf16x8*)(bp + 64 * 8);
        bf16x8 bb = *(const bf16x8*)(bp + 128 * 8);
        bf16x8 b3 = *(const bf16x8*)(bp + 192 * 8);
        f32x4 a = (f32x4){0.f, 0.f, 0.f, 0.f};
        a = __builtin_amdgcn_mfma_f32_16x16x32_bf16(a0, b0, a, 0, 0, 0);
        a = __builtin_amdgcn_mfma_f32_16x16x32_bf16(a1, b1, a, 0, 0, 0);
        a = __builtin_amdgcn_mfma_f32_16x16x32_bf16(a2, bb, a, 0, 0, 0);
        a = __builtin_amdgcn_mfma_f32_16x16x32_bf16(a3, b3, a, 0, 0, 0);
        int col = c * 16 + m;
        float bv = b2[col];
#pragma unroll
        for (int i = 0; i < 4; i++)
            ct[quad * 4 + i][col] = a[i] + bv;
    }
    __syncthreads();

    // head: 8 graphs per block; 32 threads per graph, 4 output feats each
    int gl = tid >> 5, jq = tid & 31, j4 = jq * 4;
    int g = t * 8 + gl;
    float4 h = *(const float4*)(l1b + j4);
    const float* r0 = &ct[2 * gl][0];
    const float* r1 = &ct[2 * gl + 1][0];
#pragma unroll 4
    for (int k = 0; k < H; k++) {
        float pk = r0[k] * r1[k];
        float4 wv4 = *(const float4*)(l1w + (size_t)k * H + j4);
        h.x += pk * wv4.x; h.y += pk * wv4.y;
        h.z += pk * wv4.z; h.w += pk * wv4.w;
    }
    float4 l2v = *(const float4*)(l2w + j4);
    float s = fmaxf(h.x, 0.f) * l2v.x + fmaxf(h.y, 0.f) * l2v.y +
              fmaxf(h.z, 0.f) * l2v.z + fmaxf(h.w, 0.f) * l2v.w;
#pragma unroll
    for (int d = 16; d > 0; d >>= 1) s += __shfl_xor(s, d, 32);
    if (jq == 0 && g < N_GRAPHS) out[g] = s + l2b[0];
}

extern "C" void kernel_launch(void* const* d_in, const int* in_sizes, int n_in,
                              void* d_out, int out_size, void* d_ws, size_t ws_size,
                              hipStream_t stream) {
    const int*   z    = (const int*)d_in[0];
    const int*   esrc = (const int*)d_in[1];
    const int*   edst = ((const int*)d_in[1]) + N_EDGES;
    const int*   mask = (const int*)d_in[3];
    const float* ztab = (const float*)d_in[4];
    const float* W0   = (const float*)d_in[5];
    const float* b0   = (const float*)d_in[6];
    const float* W1   = (const float*)d_in[7];
    const float* b1   = (const float*)d_in[8];
    const float* W2   = (const float*)d_in[9];
    const float* b2   = (const float*)d_in[10];
    const float* l1w  = (const float*)d_in[11];
    const float* l1b  = (const float*)d_in[12];
    const float* l2w  = (const float*)d_in[13];
    const float* l2b  = (const float*)d_in[14];
    float* out = (float*)d_out;

    char* w = (char*)d_ws;
    size_t o = 0;
    auto carve = [&](size_t bytes) { char* p = w + o; o = (o + bytes + 255) & ~(size_t)255; return p; };
    // zero-group first: one memset covers deg/fill/flags/counters
    int*            deg   = (int*)carve((size_t)N_NODES * 4);
    int*            fill  = (int*)carve((size_t)N_NODES * 4);
    int*            f0    = (int*)carve((size_t)N_NODES * 4);
    int*            f1    = (int*)carve((size_t)N_NODES * 4);
    int*            ctrs  = (int*)carve(512);
    const size_t zero_span = o;
    int*            ell   = (int*)carve((size_t)N_NODES * ELL_CAP * 4);
    int*            list0 = (int*)carve((size_t)N_NODES * 4);
    int*            list1 = (int*)carve((size_t)40000 * 4);
    unsigned short* xb    = (unsigned short*)carve((size_t)N_NODES * H * 2);
    unsigned short* xc    = (unsigned short*)carve((size_t)N_NODES * H * 2);
    unsigned short* Wp    = (unsigned short*)carve((size_t)3 * 16384 * 2);
    unsigned short* T0    = (unsigned short*)carve((size_t)MAX_Z * H * 2);

    hipMemsetAsync(d_ws, 0, zero_span, stream);
    // pass 1: degree count (no-return atomics) + center ELL + T0 GEMM + Wpack
    k_front<<<EB + 63 + 16, 256, 0, stream>>>(esrc, edst, mask, deg, fill, ell,
                                              ztab, W0, W1, W2, Wp, T0);
    // frontier N1 from center ELL
    k_n1<<<(2 * N_GRAPHS + 3) / 4, 256, 0, stream>>>(deg, ell, f1, f0, list1, list0, ctrs);
    // pass 2: ELL for non-center N1
    k_scan2<<<EB, 256, 0, stream>>>(esrc, edst, mask, f1, fill, ell);
    // frontier N0 from N1 ELL
    k_n0<<<N0_GRID, 256, 0, stream>>>(deg, ell, list1, f0, list0, ctrs);
    // pass 3: ELL for N0 \ N1
    k_scan3<<<EB, 256, 0, stream>>>(esrc, edst, mask, f0, f1, fill, ell);
    // layer 0 (N0 rows): T0-row aggregation + bias + ReLU -> xb
    k_agg0<<<AG_GRID, 256, 0, stream>>>(z, T0, ell, deg, list0, &ctrs[CTR0], b0, xb);
    // layer 1 (N1 rows): read xb, write xc
    k_layerB<<<LB_GRID, 512, 0, stream>>>(xb, ell, deg, list1, &ctrs[CTR1],
                                          Wp + 16384, b1, xc);
    // layer 2 + pooling + MLP head (reads xc)
    k_layer2<<<63, 256, 0, stream>>>(xc, ell, deg, Wp + 32768, b2,
                                     l1w, l1b, l2w, l2b, out);
}